// Round 13
// baseline (792.613 us; speedup 1.0000x reference)
//
#include <hip/hip_runtime.h>
#include <hip/hip_bf16.h>

#define N_NODES 100000
#define NBUK 391        // ceil(N_NODES / 256)
#define CHUNK 4096      // edges per hist1/binA block

typedef unsigned short ushort_t;
typedef unsigned char uchar_t;
typedef __attribute__((ext_vector_type(8))) short bf16x8;
typedef __attribute__((ext_vector_type(4))) float f32x4;
typedef __attribute__((ext_vector_type(2))) float f32x2;

// ---------------- helpers ----------------
__device__ inline float bfbits2f(unsigned int lo16) { return __uint_as_float(lo16 << 16); }

__device__ inline ushort_t f2bfbits(float f) {
    __hip_bfloat16 h = __float2bfloat16(f);
    return *reinterpret_cast<ushort_t*>(&h);
}

__device__ inline uchar_t f2fp8(float f) {
    int p = __builtin_amdgcn_cvt_pk_fp8_f32(f, 0.0f, 0, false);
    return (uchar_t)(p & 0xff);
}

__device__ inline void acc4_fp8(float* a, unsigned int u) {
    f32x2 f01 = __builtin_amdgcn_cvt_pk_f32_fp8(u, false);
    f32x2 f23 = __builtin_amdgcn_cvt_pk_f32_fp8(u, true);
    a[0] += f01.x; a[1] += f01.y; a[2] += f23.x; a[3] += f23.y;
}

// ---------------- exclusive scan (3 kernels) ----------------
__global__ __launch_bounds__(256) void scan1(const int* __restrict__ in, int* __restrict__ out,
                                             int* __restrict__ bsum, int n) {
    __shared__ int lds[256];
    const int t = threadIdx.x;
    const int base = blockIdx.x * 1024 + t * 4;
    int4 v = {0, 0, 0, 0};
    if (base + 3 < n) v = *(const int4*)(in + base);
    else {
        v.x = (base + 0 < n) ? in[base + 0] : 0;
        v.y = (base + 1 < n) ? in[base + 1] : 0;
        v.z = (base + 2 < n) ? in[base + 2] : 0;
        v.w = (base + 3 < n) ? in[base + 3] : 0;
    }
    int s0 = v.x, s1 = s0 + v.y, s2 = s1 + v.z, s3 = s2 + v.w;
    lds[t] = s3;
    __syncthreads();
    for (int off = 1; off < 256; off <<= 1) {
        int a = (t >= off) ? lds[t - off] : 0;
        __syncthreads();
        lds[t] += a;
        __syncthreads();
    }
    const int texcl = lds[t] - s3;
    if (t == 255) bsum[blockIdx.x] = lds[255];
    if (base + 0 < n) out[base + 0] = texcl;
    if (base + 1 < n) out[base + 1] = texcl + s0;
    if (base + 2 < n) out[base + 2] = texcl + s1;
    if (base + 3 < n) out[base + 3] = texcl + s2;
}

__global__ __launch_bounds__(256) void scan2(int* __restrict__ bsum, int nb) {
    __shared__ int lds[256];
    const int t = threadIdx.x;
    int v = (t < nb) ? bsum[t] : 0;
    lds[t] = v;
    __syncthreads();
    for (int off = 1; off < 256; off <<= 1) {
        int a = (t >= off) ? lds[t - off] : 0;
        __syncthreads();
        lds[t] += a;
        __syncthreads();
    }
    if (t < nb) bsum[t] = lds[t] - v;
}

__global__ void scan3(int* __restrict__ out, const int* __restrict__ bsum, int n, int E) {
    int i = blockIdx.x * blockDim.x + threadIdx.x;
    if (i < n) out[i] += bsum[i >> 10];
    if (i == 0) out[n] = E;
}

// ---------------- bucket sort ----------------
__global__ __launch_bounds__(256) void hist1(const int* __restrict__ dst, int* __restrict__ H,
                                             int E, int NC) {
    __shared__ int h[NBUK + 1];
    const int t = threadIdx.x, c = blockIdx.x;
    for (int g = t; g <= NBUK; g += 256) h[g] = 0;
    __syncthreads();
    const long base = (long)c * CHUNK;
#pragma unroll 4
    for (int it = 0; it < CHUNK / 256; ++it) {
        long e = base + it * 256 + t;
        if (e < E) atomicAdd(&h[((unsigned)dst[e]) >> 8], 1);
    }
    __syncthreads();
    for (int g = t; g < NBUK; g += 256) H[(size_t)g * NC + c] = h[g];
}

__global__ __launch_bounds__(256) void binA(const int* __restrict__ src,
                                            const int* __restrict__ dst,
                                            const int* __restrict__ Hs,  // scanned
                                            uint2* __restrict__ tmp, int E, int NC) {
    __shared__ int cur[NBUK + 1];
    const int t = threadIdx.x, c = blockIdx.x;
    for (int g = t; g < NBUK; g += 256) cur[g] = Hs[(size_t)g * NC + c];
    __syncthreads();
    const long cb = (long)c * CHUNK;
#pragma unroll 4
    for (int it = 0; it < CHUNK / 256; ++it) {
        long e = cb + it * 256 + t;
        if (e < E) {
            unsigned d = (unsigned)dst[e];
            int pos = atomicAdd(&cur[d >> 8], 1);
            uint2 p = {d, (unsigned)src[e]};
            tmp[pos] = p;
        }
    }
}

// fine histogram -> per-node counts + reciprocal (fused)
__global__ __launch_bounds__(256) void hist2_inv(const uint2* __restrict__ tmp,
                                                 const int* __restrict__ Hs,
                                                 int* __restrict__ cnt,
                                                 float* __restrict__ invd, int NC) {
    __shared__ int h[256];
    const int t = threadIdx.x, b = blockIdx.x;
    h[t] = 0;
    __syncthreads();
    const int beg = Hs[(size_t)b * NC], end = Hs[(size_t)(b + 1) * NC];
    for (int e = beg + t; e < end; e += 256) atomicAdd(&h[tmp[e].x & 255u], 1);
    __syncthreads();
    const int d = b * 256 + t;
    if (d < N_NODES) {
        cnt[d] = h[t];
        invd[d] = 1.0f / (float)max(h[t], 1);
    }
}

__global__ __launch_bounds__(256) void scatter2(const uint2* __restrict__ tmp,
                                                const int* __restrict__ Hs,
                                                const int* __restrict__ roff,
                                                int* __restrict__ csr, int NC) {
    __shared__ int cur[256];
    const int t = threadIdx.x, b = blockIdx.x;
    const int d = b * 256 + t;
    cur[t] = (d <= N_NODES) ? roff[min(d, N_NODES)] : 0;
    __syncthreads();
    const int beg = Hs[(size_t)b * NC], end = Hs[(size_t)(b + 1) * NC];
    for (int e = beg + t; e < end; e += 256) {
        uint2 p = tmp[e];
        int pos = atomicAdd(&cur[p.x & 255u], 1);
        csr[pos] = (int)p.y;
    }
}

// ---------------- rounding: one x read -> bf16 + fp8 ----------------
__global__ void round_both(const float* __restrict__ x, ushort_t* __restrict__ xb,
                           uchar_t* __restrict__ x8, long n) {
    long i = ((long)blockIdx.x * blockDim.x + threadIdx.x) * 4;
    if (i < n) {
        float4 v = *(const float4*)(x + i);
        ushort4 o = {f2bfbits(v.x), f2bfbits(v.y), f2bfbits(v.z), f2bfbits(v.w)};
        *(ushort4*)(xb + i) = o;
        int w = __builtin_amdgcn_cvt_pk_fp8_f32(v.x, v.y, 0, false);
        w = __builtin_amdgcn_cvt_pk_fp8_f32(v.z, v.w, w, true);
        *(unsigned int*)(x8 + i) = (unsigned int)w;
    }
}

// ---------------- weight cvt + transpose ----------------
__global__ void cvt_transpose(const float* __restrict__ W, ushort_t* __restrict__ WT,
                              int K, int J, int kdst0, int ldwt) {
    int idx = blockIdx.x * blockDim.x + threadIdx.x;
    if (idx >= K * J) return;
    int k = idx / J, j = idx - k * J;
    WT[(size_t)j * ldwt + kdst0 + k] = f2bfbits(W[idx]);
}

// 6 column-slice transposes in one launch (blockIdx.y selects job)
__global__ void cvt6(const float* __restrict__ Wl2, const float* __restrict__ Wr2,
                     const float* __restrict__ Wl3, const float* __restrict__ Wr3,
                     ushort_t* __restrict__ WT2A, ushort_t* __restrict__ WT2B,
                     ushort_t* __restrict__ WT3) {
    const int y = blockIdx.y;
    int idx = blockIdx.x * blockDim.x + threadIdx.x;
    if (idx >= 256 * 128) return;
    int k = idx >> 7, jj = idx & 127;
    const float* W;
    ushort_t* WT;
    int J = 256, jsrc0 = 0;
    switch (y) {
        case 0: W = Wl2; WT = WT2A; break;
        case 1: W = Wr2; WT = WT2A; break;
        case 2: W = Wl2; WT = WT2B; jsrc0 = 128; break;
        case 3: W = Wr2; WT = WT2B; jsrc0 = 128; break;
        case 4: W = Wl3; WT = WT3; J = 128; break;
        default: W = Wr3; WT = WT3; J = 128; break;
    }
    const int row0 = (y & 1) * 128;
    WT[(size_t)(row0 + jj) * 256 + k] = f2bfbits(W[(size_t)k * J + jsrc0 + jj]);
}

// ---------------- XCD-sliced gather-mean (fp8 Y rows) ----------------
// Column-sliced so each XCD's L2 caches one 32-byte slice of Y (3.2 MB < 4 MB).
// blockIdx%8 -> XCD (round-robin heuristic; perf-only, not correctness).
// NCOLS=256: 8 slices; NCOLS=128: 4 slices, XCD pairs share a slice, nodes split 2x.
// Block = 4 waves = 4 nodes. Wave = 8 edge-groups x 8 lanes x 4B (one 32B req/edge).
// ADDZ: out = relu(mean*inv + Z[node][cols]) ; else out = mean*inv.
template <int NCOLS, bool ADDZ, typename OT>
__global__ __launch_bounds__(256) void gather_sl(const uchar_t* __restrict__ Y,
                                                 const ushort_t* __restrict__ Z,
                                                 const int* __restrict__ roff,
                                                 const int* __restrict__ csr,
                                                 const float* __restrict__ invd,
                                                 OT* __restrict__ out) {
    const int bx = blockIdx.x;
    const int s8 = bx & 7;
    int slice, ng;
    if (NCOLS == 256) { slice = s8; ng = bx >> 3; }
    else { slice = s8 & 3; ng = ((bx >> 3) << 1) | (s8 >> 2); }

    const int node = ng * 4 + (threadIdx.x >> 6);
    if (node >= N_NODES) return;
    const int lane = threadIdx.x & 63;
    const int g = lane >> 3;      // edge group 0..7
    const int li = lane & 7;      // 4B chunk within 32B slice
    const int e0 = roff[node], e1 = roff[node + 1];
    const size_t coff = (size_t)slice * 32 + li * 4;   // byte offset within fp8 row

    float a[4] = {0.f, 0.f, 0.f, 0.f};

    int e = e0 + g;
    for (; e + 8 < e1; e += 16) {
        unsigned int u0 = *(const unsigned int*)(Y + (size_t)csr[e] * NCOLS + coff);
        unsigned int u1 = *(const unsigned int*)(Y + (size_t)csr[e + 8] * NCOLS + coff);
        acc4_fp8(a, u0);
        acc4_fp8(a, u1);
    }
    if (e < e1) {
        unsigned int u0 = *(const unsigned int*)(Y + (size_t)csr[e] * NCOLS + coff);
        acc4_fp8(a, u0);
    }

    // reduce across the 8 groups
#pragma unroll
    for (int i = 0; i < 4; ++i) {
        a[i] += __shfl_xor(a[i], 8);
        a[i] += __shfl_xor(a[i], 16);
        a[i] += __shfl_xor(a[i], 32);
    }

    if (g != 0) return;
    const float iv = invd[node];
#pragma unroll
    for (int i = 0; i < 4; ++i) a[i] *= iv;

    if constexpr (ADDZ) {
        uint2 z = *(const uint2*)(Z + (size_t)node * NCOLS + slice * 32 + li * 4);
        float zf[4];
        zf[0] = bfbits2f(z.x & 0xffffu); zf[1] = __uint_as_float(z.x & 0xffff0000u);
        zf[2] = bfbits2f(z.y & 0xffffu); zf[3] = __uint_as_float(z.y & 0xffff0000u);
#pragma unroll
        for (int i = 0; i < 4; ++i) a[i] = fmaxf(a[i] + zf[i], 0.0f);
    }

    if constexpr (sizeof(OT) == 4) {  // f32 out (stride 128)
        float4 st = {a[0], a[1], a[2], a[3]};
        *(float4*)((float*)out + (size_t)node * 128 + slice * 32 + li * 4) = st;
    } else {  // bf16 out (stride NCOLS)
        ushort4 st = {f2bfbits(a[0]), f2bfbits(a[1]), f2bfbits(a[2]), f2bfbits(a[3])};
        *(ushort4*)((ushort_t*)out + (size_t)node * NCOLS + slice * 32 + li * 4) = st;
    }
}

// ---------------- merged MFMA GEMM, 2-phase double-buffered ----------------
// 128 rows x 256 out-cols per block; BK=32, NT=KTOT/32 tiles, dbuf LDS 2x24KB.
// MODE 0 (L1): out0 = relu(acc + bias[col]) over 256 bf16 cols.
// MODE 1 (dual): out0[lcol] = fp8(acc0); out1[lcol] = bf16(acc1 + bias[lcol]).
template <int KH, bool CONCAT, int MODE>
__global__ __launch_bounds__(256) void mfma_gemm256(const ushort_t* __restrict__ A,
                                                    const ushort_t* __restrict__ A2,
                                                    const ushort_t* __restrict__ WT,
                                                    const float* __restrict__ bias,
                                                    void* __restrict__ out0p, int ld0,
                                                    ushort_t* __restrict__ out1, int ld1) {
    constexpr int KTOT = CONCAT ? 2 * KH : KH;
    constexpr int BK = 32;
    constexpr int NT = KTOT / BK;
    __shared__ ushort_t smem[2][12288];   // per buf: A 4096 ush (8KB) + B 8192 ush (16KB)

    const int tid = threadIdx.x;
    const int lane = tid & 63;
    const int w = tid >> 6;
    const int wr = w >> 1, wc = w & 1;
    const int n0 = blockIdx.x * 128;

    const int srow = lane >> 2;                       // 0..15 row within chunk
    const int skc = (lane & 3) ^ ((srow >> 1) & 3);   // pre-swizzled 16B slot

    f32x4 acc0[4][4], acc1[4][4];
#pragma unroll
    for (int m = 0; m < 4; ++m)
#pragma unroll
        for (int n = 0; n < 4; ++n) {
            acc0[m][n] = (f32x4){0.f, 0.f, 0.f, 0.f};
            acc1[m][n] = (f32x4){0.f, 0.f, 0.f, 0.f};
        }

    auto STAGE = [&](int b, int t) {
        const int k0 = t * BK;
        const ushort_t* Asrc = A;
        int ak = k0;
        if (CONCAT && k0 >= KH) { Asrc = A2; ak = k0 - KH; }
#pragma unroll
        for (int i = 0; i < 2; ++i) {
            const int ci = w * 2 + i;
            int grow = n0 + ci * 16 + srow;
            grow = min(grow, N_NODES - 1);
            const ushort_t* g = Asrc + (size_t)grow * KH + ak + skc * 8;
            __builtin_amdgcn_global_load_lds((const unsigned int*)g,
                                             (unsigned int*)(&smem[b][ci * 512]), 16, 0, 0);
        }
#pragma unroll
        for (int i = 0; i < 4; ++i) {
            const int ci = w * 4 + i;
            const int jrow = ci * 16 + srow;
            const ushort_t* g = WT + (size_t)jrow * KTOT + k0 + skc * 8;
            __builtin_amdgcn_global_load_lds((const unsigned int*)g,
                                             (unsigned int*)(&smem[b][4096 + ci * 512]), 16, 0, 0);
        }
    };

    auto COMPUTE = [&](int b) {
        const int kc = lane >> 4;
        bf16x8 af[4], b0[4], b1[4];
#pragma unroll
        for (int m = 0; m < 4; ++m) {
            const int row = wr * 64 + m * 16 + (lane & 15);
            const int slot = kc ^ ((row >> 1) & 3);
            af[m] = *(const bf16x8*)((const char*)&smem[b][0] + row * 64 + slot * 16);
        }
#pragma unroll
        for (int n = 0; n < 4; ++n) {
            const int r0 = wc * 64 + n * 16 + (lane & 15);
            const int r1 = 128 + r0;
            const int s0 = kc ^ ((r0 >> 1) & 3);
            const int s1 = kc ^ ((r1 >> 1) & 3);
            b0[n] = *(const bf16x8*)((const char*)&smem[b][4096] + r0 * 64 + s0 * 16);
            b1[n] = *(const bf16x8*)((const char*)&smem[b][4096] + r1 * 64 + s1 * 16);
        }
#pragma unroll
        for (int m = 0; m < 4; ++m)
#pragma unroll
            for (int n = 0; n < 4; ++n) {
                acc0[m][n] = __builtin_amdgcn_mfma_f32_16x16x32_bf16(af[m], b0[n],
                                                                     acc0[m][n], 0, 0, 0);
                acc1[m][n] = __builtin_amdgcn_mfma_f32_16x16x32_bf16(af[m], b1[n],
                                                                     acc1[m][n], 0, 0, 0);
            }
    };

    STAGE(0, 0);
    __syncthreads();
    int cur = 0;
#pragma unroll
    for (int t = 0; t < NT - 1; ++t) {
        STAGE(cur ^ 1, t + 1);
        COMPUTE(cur);
        __syncthreads();
        cur ^= 1;
    }
    COMPUTE(cur);

    const int c15 = lane & 15;
    const int r4 = (lane >> 4) * 4;
#pragma unroll
    for (int m = 0; m < 4; ++m) {
#pragma unroll
        for (int q = 0; q < 4; ++q) {
            const int row_g = n0 + wr * 64 + m * 16 + r4 + q;
            if (row_g >= N_NODES) continue;
#pragma unroll
            for (int n = 0; n < 4; ++n) {
                const int lcol = wc * 64 + n * 16 + c15;
                const float v0 = acc0[m][n][q];
                const float v1 = acc1[m][n][q];
                if constexpr (MODE == 0) {
                    ushort_t* o = (ushort_t*)out0p;
                    o[(size_t)row_g * ld0 + lcol] = f2bfbits(fmaxf(v0 + bias[lcol], 0.0f));
                    o[(size_t)row_g * ld0 + 128 + lcol] =
                        f2bfbits(fmaxf(v1 + bias[128 + lcol], 0.0f));
                } else {
                    ((uchar_t*)out0p)[(size_t)row_g * ld0 + lcol] = f2fp8(v0);
                    out1[(size_t)row_g * ld1 + lcol] = f2bfbits(v1 + bias[lcol]);
                }
            }
        }
    }
}

// ---------------- launch ----------------
extern "C" void kernel_launch(void* const* d_in, const int* in_sizes, int n_in,
                              void* d_out, int out_size, void* d_ws, size_t ws_size,
                              hipStream_t stream) {
    const float* x   = (const float*)d_in[0];
    const int*   ei  = (const int*)d_in[1];
    const float* Wl1 = (const float*)d_in[2];
    const float* Wr1 = (const float*)d_in[3];
    const float* b1  = (const float*)d_in[4];
    const float* Wl2 = (const float*)d_in[5];
    const float* Wr2 = (const float*)d_in[6];
    const float* b2  = (const float*)d_in[7];
    const float* Wl3 = (const float*)d_in[8];
    const float* Wr3 = (const float*)d_in[9];
    const float* b3  = (const float*)d_in[10];

    const int E = in_sizes[1] / 2;
    const int* src = ei;
    const int* dst = ei + E;
    const int N = N_NODES;
    const int NC = (E + CHUNK - 1) / CHUNK;        // 391 @ 1.6M
    const int nH = NBUK * NC;                       // 152,881

    // ---- workspace arena (149.6 MB; 154.6 MB proven available) ----
    char* ws = (char*)d_ws;
    float* invd = (float*)(ws + 0);                  // 400,000
    int* cnt    = (int*)(ws + 400000);               // 400,000
    int* roff   = (int*)(ws + 800000);               // 400,016
    int* bsum   = (int*)(ws + 1200016);              // 1,024
    int* H      = (int*)(ws + 1201040);              // (nH+1)*4 = 611,528
    ushort_t* WT1  = (ushort_t*)(ws + 1812568);      // 131,072 (L1 k-concat, 256 rows)
    ushort_t* WT2A = (ushort_t*)(ws + 1943640);      // 131,072
    ushort_t* WT2B = (ushort_t*)(ws + 2074712);      // 131,072
    ushort_t* WT3  = (ushort_t*)(ws + 2205784);      // 131,072
    uint2* tmp  = (uint2*)(ws + 2336864);            // 12,800,000 (CSR build; then fp8 Y 128c)
    int* csr    = (int*)(ws + 15136864);             // 6,400,000
    ushort_t* h1 = (ushort_t*)(ws + 21536864);       // 51,200,000
    ushort_t* h2 = (ushort_t*)(ws + 72736864);       // 51,200,000
    ushort_t* M1 = h2;                                // alias (dead during L1)
    ushort_t* T1 = (ushort_t*)(ws + 123936864);      // 25,600,000 (bf16 x; then fp8 Y2 256c)
    const size_t WS_NEED = 149536864;
    if (ws_size < WS_NEED) return;

    uchar_t* T8  = (uchar_t*)tmp;      // 128-col fp8 rows (x in L1, Y3 in L3)
    uchar_t* T1a = (uchar_t*)T1;       // 256-col fp8 Y2 rows (L2; T1 dead after L1 GEMM)
    ushort_t* Zd = (ushort_t*)d_out;   // L2 Z scratch, N x 256 bf16 (d_out dead until L3)
    ushort_t* Zh = h1;                 // L3 Z scratch (h1 dead after L2)

    const int GX = (N + 127) / 128;
    const int NBH = (nH + 1023) / 1024;   // 150
    const int NBN = (N + 1023) / 1024;    // 98
    const int G128 = 8 * ((N + 7) / 8);   // sliced-gather grid, 128-col (4 slices x 2 halves)
    const int G256 = 8 * ((N + 3) / 4);   // sliced-gather grid, 256-col (8 slices)

    // ---- CSR build: atomic-free two-level bucket sort (10 launches) ----
    hist1<<<NC, 256, 0, stream>>>(dst, H, E, NC);
    scan1<<<NBH, 256, 0, stream>>>(H, H, bsum, nH);
    scan2<<<1, 256, 0, stream>>>(bsum, NBH);
    scan3<<<(nH + 256) / 256, 256, 0, stream>>>(H, bsum, nH, E);
    binA<<<NC, 256, 0, stream>>>(src, dst, H, tmp, E, NC);
    hist2_inv<<<NBUK, 256, 0, stream>>>(tmp, H, cnt, invd, NC);
    scan1<<<NBN, 256, 0, stream>>>(cnt, roff, bsum, N);
    scan2<<<1, 256, 0, stream>>>(bsum, NBN);
    scan3<<<(N + 256) / 256, 256, 0, stream>>>(roff, bsum, N, E);
    scatter2<<<NBUK, 256, 0, stream>>>(tmp, H, roff, csr, NC);

    // ---- weight prep (3 launches) ----
    cvt_transpose<<<(128 * 256 + 255) / 256, 256, 0, stream>>>(Wl1, WT1, 128, 256, 0, 256);
    cvt_transpose<<<(128 * 256 + 255) / 256, 256, 0, stream>>>(Wr1, WT1, 128, 256, 128, 256);
    cvt6<<<dim3(128, 6), 256, 0, stream>>>(Wl2, Wr2, Wl3, Wr3, WT2A, WT2B, WT3);

    // ---- layer 1: fp8 XCD-sliced aggregate + merged concat GEMM ----
    round_both<<<(N * 128 / 4 + 255) / 256, 256, 0, stream>>>(x, T1, T8, (long)N * 128);
    gather_sl<128, false, ushort_t><<<G128, 256, 0, stream>>>(
        T8, nullptr, roff, csr, invd, M1);
    mfma_gemm256<128, true, 0><<<GX, 256, 0, stream>>>(
        M1, T1, WT1, b1, h1, 256, nullptr, 0);

    // ---- layer 2: 2 dual GEMMs into full-width Y2/Z2, then ONE sliced 256-col gather ----
    mfma_gemm256<256, false, 1><<<GX, 256, 0, stream>>>(
        h1, nullptr, WT2A, b2 + 0, T1a, 256, Zd, 256);
    mfma_gemm256<256, false, 1><<<GX, 256, 0, stream>>>(
        h1, nullptr, WT2B, b2 + 128, T1a + 128, 256, Zd + 128, 256);
    gather_sl<256, true, ushort_t><<<G256, 256, 0, stream>>>(
        T1a, Zd, roff, csr, invd, h2);

    // ---- layer 3: dual GEMM (Y3 fp8 -> T8, Z -> Zh) + sliced gather, f32 out ----
    mfma_gemm256<256, false, 1><<<GX, 256, 0, stream>>>(
        h2, nullptr, WT3, b3, T8, 128, Zh, 128);
    gather_sl<128, true, float><<<G128, 256, 0, stream>>>(
        T8, Zh, roff, csr, invd, (float*)d_out);
}

// Round 14
// 445.941 us; speedup vs baseline: 1.7774x; 1.7774x over previous
//
#include <hip/hip_runtime.h>
#include <hip/hip_bf16.h>

#define N_NODES 100000
#define NBUK 391        // ceil(N_NODES / 256)
#define CHUNK 4096      // edges per hist1/binA block

typedef unsigned short ushort_t;
typedef unsigned char uchar_t;
typedef __attribute__((ext_vector_type(8))) short bf16x8;
typedef __attribute__((ext_vector_type(4))) float f32x4;
typedef __attribute__((ext_vector_type(2))) float f32x2;

// ---------------- helpers ----------------
__device__ inline float bfbits2f(unsigned int lo16) { return __uint_as_float(lo16 << 16); }

__device__ inline ushort_t f2bfbits(float f) {
    __hip_bfloat16 h = __float2bfloat16(f);
    return *reinterpret_cast<ushort_t*>(&h);
}

__device__ inline unsigned int pk2bf(float lo, float hi) {
    return (unsigned int)f2bfbits(lo) | ((unsigned int)f2bfbits(hi) << 16);
}

__device__ inline uchar_t f2fp8(float f) {
    int p = __builtin_amdgcn_cvt_pk_fp8_f32(f, 0.0f, 0, false);
    return (uchar_t)(p & 0xff);
}

__device__ inline void acc8_fp8(float* a, unsigned int ux, unsigned int uy) {
    f32x2 f01 = __builtin_amdgcn_cvt_pk_f32_fp8(ux, false);
    f32x2 f23 = __builtin_amdgcn_cvt_pk_f32_fp8(ux, true);
    f32x2 f45 = __builtin_amdgcn_cvt_pk_f32_fp8(uy, false);
    f32x2 f67 = __builtin_amdgcn_cvt_pk_f32_fp8(uy, true);
    a[0] += f01.x; a[1] += f01.y; a[2] += f23.x; a[3] += f23.y;
    a[4] += f45.x; a[5] += f45.y; a[6] += f67.x; a[7] += f67.y;
}

__device__ inline void acc16_fp8(float* a, uint4 u) {
    acc8_fp8(a, u.x, u.y);
    acc8_fp8(a + 8, u.z, u.w);
}

// ---------------- exclusive scan (3 kernels) ----------------
__global__ __launch_bounds__(256) void scan1(const int* __restrict__ in, int* __restrict__ out,
                                             int* __restrict__ bsum, int n) {
    __shared__ int lds[256];
    const int t = threadIdx.x;
    const int base = blockIdx.x * 1024 + t * 4;
    int4 v = {0, 0, 0, 0};
    if (base + 3 < n) v = *(const int4*)(in + base);
    else {
        v.x = (base + 0 < n) ? in[base + 0] : 0;
        v.y = (base + 1 < n) ? in[base + 1] : 0;
        v.z = (base + 2 < n) ? in[base + 2] : 0;
        v.w = (base + 3 < n) ? in[base + 3] : 0;
    }
    int s0 = v.x, s1 = s0 + v.y, s2 = s1 + v.z, s3 = s2 + v.w;
    lds[t] = s3;
    __syncthreads();
    for (int off = 1; off < 256; off <<= 1) {
        int a = (t >= off) ? lds[t - off] : 0;
        __syncthreads();
        lds[t] += a;
        __syncthreads();
    }
    const int texcl = lds[t] - s3;
    if (t == 255) bsum[blockIdx.x] = lds[255];
    if (base + 0 < n) out[base + 0] = texcl;
    if (base + 1 < n) out[base + 1] = texcl + s0;
    if (base + 2 < n) out[base + 2] = texcl + s1;
    if (base + 3 < n) out[base + 3] = texcl + s2;
}

__global__ __launch_bounds__(256) void scan2(int* __restrict__ bsum, int nb) {
    __shared__ int lds[256];
    const int t = threadIdx.x;
    int v = (t < nb) ? bsum[t] : 0;
    lds[t] = v;
    __syncthreads();
    for (int off = 1; off < 256; off <<= 1) {
        int a = (t >= off) ? lds[t - off] : 0;
        __syncthreads();
        lds[t] += a;
        __syncthreads();
    }
    if (t < nb) bsum[t] = lds[t] - v;
}

__global__ void scan3(int* __restrict__ out, const int* __restrict__ bsum, int n, int E) {
    int i = blockIdx.x * blockDim.x + threadIdx.x;
    if (i < n) out[i] += bsum[i >> 10];
    if (i == 0) out[n] = E;
}

// ---------------- bucket sort ----------------
__global__ __launch_bounds__(256) void hist1(const int* __restrict__ dst, int* __restrict__ H,
                                             int E, int NC) {
    __shared__ int h[NBUK + 1];
    const int t = threadIdx.x, c = blockIdx.x;
    for (int g = t; g <= NBUK; g += 256) h[g] = 0;
    __syncthreads();
    const long base = (long)c * CHUNK;
#pragma unroll 4
    for (int it = 0; it < CHUNK / 256; ++it) {
        long e = base + it * 256 + t;
        if (e < E) atomicAdd(&h[((unsigned)dst[e]) >> 8], 1);
    }
    __syncthreads();
    for (int g = t; g < NBUK; g += 256) H[(size_t)g * NC + c] = h[g];
}

__global__ __launch_bounds__(256) void binA(const int* __restrict__ src,
                                            const int* __restrict__ dst,
                                            const int* __restrict__ Hs,  // scanned
                                            uint2* __restrict__ tmp, int E, int NC) {
    __shared__ int cur[NBUK + 1];
    const int t = threadIdx.x, c = blockIdx.x;
    for (int g = t; g < NBUK; g += 256) cur[g] = Hs[(size_t)g * NC + c];
    __syncthreads();
    const long cb = (long)c * CHUNK;
#pragma unroll 4
    for (int it = 0; it < CHUNK / 256; ++it) {
        long e = cb + it * 256 + t;
        if (e < E) {
            unsigned d = (unsigned)dst[e];
            int pos = atomicAdd(&cur[d >> 8], 1);
            uint2 p = {d, (unsigned)src[e]};
            tmp[pos] = p;
        }
    }
}

// fine histogram -> per-node counts + reciprocal (fused)
__global__ __launch_bounds__(256) void hist2_inv(const uint2* __restrict__ tmp,
                                                 const int* __restrict__ Hs,
                                                 int* __restrict__ cnt,
                                                 float* __restrict__ invd, int NC) {
    __shared__ int h[256];
    const int t = threadIdx.x, b = blockIdx.x;
    h[t] = 0;
    __syncthreads();
    const int beg = Hs[(size_t)b * NC], end = Hs[(size_t)(b + 1) * NC];
    for (int e = beg + t; e < end; e += 256) atomicAdd(&h[tmp[e].x & 255u], 1);
    __syncthreads();
    const int d = b * 256 + t;
    if (d < N_NODES) {
        cnt[d] = h[t];
        invd[d] = 1.0f / (float)max(h[t], 1);
    }
}

__global__ __launch_bounds__(256) void scatter2(const uint2* __restrict__ tmp,
                                                const int* __restrict__ Hs,
                                                const int* __restrict__ roff,
                                                int* __restrict__ csr, int NC) {
    __shared__ int cur[256];
    const int t = threadIdx.x, b = blockIdx.x;
    const int d = b * 256 + t;
    cur[t] = (d <= N_NODES) ? roff[min(d, N_NODES)] : 0;
    __syncthreads();
    const int beg = Hs[(size_t)b * NC], end = Hs[(size_t)(b + 1) * NC];
    for (int e = beg + t; e < end; e += 256) {
        uint2 p = tmp[e];
        int pos = atomicAdd(&cur[p.x & 255u], 1);
        csr[pos] = (int)p.y;
    }
}

// ---------------- rounding: one x read -> bf16 + fp8 ----------------
__global__ void round_both(const float* __restrict__ x, ushort_t* __restrict__ xb,
                           uchar_t* __restrict__ x8, long n) {
    long i = ((long)blockIdx.x * blockDim.x + threadIdx.x) * 4;
    if (i < n) {
        float4 v = *(const float4*)(x + i);
        ushort4 o = {f2bfbits(v.x), f2bfbits(v.y), f2bfbits(v.z), f2bfbits(v.w)};
        *(ushort4*)(xb + i) = o;
        int w = __builtin_amdgcn_cvt_pk_fp8_f32(v.x, v.y, 0, false);
        w = __builtin_amdgcn_cvt_pk_fp8_f32(v.z, v.w, w, true);
        *(unsigned int*)(x8 + i) = (unsigned int)w;
    }
}

// ---------------- weight cvt + transpose ----------------
__global__ void cvt_transpose(const float* __restrict__ W, ushort_t* __restrict__ WT,
                              int K, int J, int kdst0, int ldwt) {
    int idx = blockIdx.x * blockDim.x + threadIdx.x;
    if (idx >= K * J) return;
    int k = idx / J, j = idx - k * J;
    WT[(size_t)j * ldwt + kdst0 + k] = f2bfbits(W[idx]);
}

// 6 column-slice transposes in one launch (blockIdx.y selects job)
__global__ void cvt6(const float* __restrict__ Wl2, const float* __restrict__ Wr2,
                     const float* __restrict__ Wl3, const float* __restrict__ Wr3,
                     ushort_t* __restrict__ WT2A, ushort_t* __restrict__ WT2B,
                     ushort_t* __restrict__ WT3) {
    const int y = blockIdx.y;
    int idx = blockIdx.x * blockDim.x + threadIdx.x;
    if (idx >= 256 * 128) return;
    int k = idx >> 7, jj = idx & 127;
    const float* W;
    ushort_t* WT;
    int J = 256, jsrc0 = 0;
    switch (y) {
        case 0: W = Wl2; WT = WT2A; break;
        case 1: W = Wr2; WT = WT2A; break;
        case 2: W = Wl2; WT = WT2B; jsrc0 = 128; break;
        case 3: W = Wr2; WT = WT2B; jsrc0 = 128; break;
        case 4: W = Wl3; WT = WT3; J = 128; break;
        default: W = Wr3; WT = WT3; J = 128; break;
    }
    const int row0 = (y & 1) * 128;
    WT[(size_t)(row0 + jj) * 256 + k] = f2bfbits(W[(size_t)k * J + jsrc0 + jj]);
}

// ---------------- gather-mean, 128-col fp8 rows (L1 & L3) ----------------
template <bool ADDZ, typename OT>
__global__ __launch_bounds__(256) void gather_mean(const uchar_t* __restrict__ Y,
                                                   const ushort_t* __restrict__ Z,
                                                   const int* __restrict__ roff,
                                                   const int* __restrict__ csr,
                                                   const float* __restrict__ invd,
                                                   OT* __restrict__ out, int out_ld, int col0) {
    const int w = (blockIdx.x * blockDim.x + threadIdx.x) >> 6;  // node
    if (w >= N_NODES) return;
    const int lane = threadIdx.x & 63;
    const int g = lane >> 4;
    const int l = lane & 15;
    const int e0 = roff[w], e1 = roff[w + 1];

    float a[8] = {0.f, 0.f, 0.f, 0.f, 0.f, 0.f, 0.f, 0.f};

    int e = e0 + g;
    for (; e + 12 < e1; e += 16) {
        const int s0 = csr[e], s1 = csr[e + 4], s2 = csr[e + 8], s3 = csr[e + 12];
        uint2 u0 = *(const uint2*)(Y + (size_t)s0 * 128 + l * 8);
        uint2 u1 = *(const uint2*)(Y + (size_t)s1 * 128 + l * 8);
        uint2 u2 = *(const uint2*)(Y + (size_t)s2 * 128 + l * 8);
        uint2 u3 = *(const uint2*)(Y + (size_t)s3 * 128 + l * 8);
        acc8_fp8(a, u0.x, u0.y); acc8_fp8(a, u1.x, u1.y);
        acc8_fp8(a, u2.x, u2.y); acc8_fp8(a, u3.x, u3.y);
    }
    for (; e < e1; e += 4) {
        uint2 u0 = *(const uint2*)(Y + (size_t)csr[e] * 128 + l * 8);
        acc8_fp8(a, u0.x, u0.y);
    }

#pragma unroll
    for (int i = 0; i < 8; ++i) {
        a[i] += __shfl_xor(a[i], 16);
        a[i] += __shfl_xor(a[i], 32);
    }

    if (g != 0) return;
    const float iv = invd[w];
#pragma unroll
    for (int i = 0; i < 8; ++i) a[i] *= iv;

    if constexpr (ADDZ) {
        uint4 z = *(const uint4*)(Z + (size_t)w * 128 + l * 8);
        float zf[8];
        zf[0] = bfbits2f(z.x & 0xffffu); zf[1] = __uint_as_float(z.x & 0xffff0000u);
        zf[2] = bfbits2f(z.y & 0xffffu); zf[3] = __uint_as_float(z.y & 0xffff0000u);
        zf[4] = bfbits2f(z.z & 0xffffu); zf[5] = __uint_as_float(z.z & 0xffff0000u);
        zf[6] = bfbits2f(z.w & 0xffffu); zf[7] = __uint_as_float(z.w & 0xffff0000u);
#pragma unroll
        for (int i = 0; i < 8; ++i) a[i] = fmaxf(a[i] + zf[i], 0.0f);
    }

    if constexpr (sizeof(OT) == 4) {
        float* op = (float*)out + (size_t)w * out_ld + col0 + l * 8;
        float4 s0 = {a[0], a[1], a[2], a[3]};
        float4 s1 = {a[4], a[5], a[6], a[7]};
        *(float4*)op = s0;
        *(float4*)(op + 4) = s1;
    } else {
        ushort_t* op = (ushort_t*)out + (size_t)w * out_ld + col0 + l * 8;
        ushort4 lohi0 = {f2bfbits(a[0]), f2bfbits(a[1]), f2bfbits(a[2]), f2bfbits(a[3])};
        ushort4 lohi1 = {f2bfbits(a[4]), f2bfbits(a[5]), f2bfbits(a[6]), f2bfbits(a[7])};
        *(ushort4*)op = lohi0;
        *(ushort4*)(op + 4) = lohi1;
    }
}

// ---------------- gather-mean, 256-col fp8 rows + Z add (L2, single pass) ----------------
__global__ __launch_bounds__(256) void gather256(const uchar_t* __restrict__ Y,
                                                 const ushort_t* __restrict__ Z,
                                                 const int* __restrict__ roff,
                                                 const int* __restrict__ csr,
                                                 const float* __restrict__ invd,
                                                 ushort_t* __restrict__ out) {
    const int w = (blockIdx.x * blockDim.x + threadIdx.x) >> 6;  // node
    if (w >= N_NODES) return;
    const int lane = threadIdx.x & 63;
    const int g = lane >> 4;   // edge group 0..3
    const int l = lane & 15;   // 16B chunk within 256B row
    const int e0 = roff[w], e1 = roff[w + 1];

    float a[16];
#pragma unroll
    for (int i = 0; i < 16; ++i) a[i] = 0.0f;

    int e = e0 + g;
    for (; e + 12 < e1; e += 16) {
        const int s0 = csr[e], s1 = csr[e + 4], s2 = csr[e + 8], s3 = csr[e + 12];
        uint4 u0 = *(const uint4*)(Y + (size_t)s0 * 256 + l * 16);
        uint4 u1 = *(const uint4*)(Y + (size_t)s1 * 256 + l * 16);
        uint4 u2 = *(const uint4*)(Y + (size_t)s2 * 256 + l * 16);
        uint4 u3 = *(const uint4*)(Y + (size_t)s3 * 256 + l * 16);
        acc16_fp8(a, u0); acc16_fp8(a, u1); acc16_fp8(a, u2); acc16_fp8(a, u3);
    }
    for (; e < e1; e += 4) {
        uint4 u0 = *(const uint4*)(Y + (size_t)csr[e] * 256 + l * 16);
        acc16_fp8(a, u0);
    }

#pragma unroll
    for (int i = 0; i < 16; ++i) {
        a[i] += __shfl_xor(a[i], 16);
        a[i] += __shfl_xor(a[i], 32);
    }

    if (g != 0) return;
    const float iv = invd[w];

    uint4 z0 = *(const uint4*)(Z + (size_t)w * 256 + l * 16);
    uint4 z1 = *(const uint4*)(Z + (size_t)w * 256 + l * 16 + 8);
    float zf[16];
    zf[0] = bfbits2f(z0.x & 0xffffu);  zf[1] = __uint_as_float(z0.x & 0xffff0000u);
    zf[2] = bfbits2f(z0.y & 0xffffu);  zf[3] = __uint_as_float(z0.y & 0xffff0000u);
    zf[4] = bfbits2f(z0.z & 0xffffu);  zf[5] = __uint_as_float(z0.z & 0xffff0000u);
    zf[6] = bfbits2f(z0.w & 0xffffu);  zf[7] = __uint_as_float(z0.w & 0xffff0000u);
    zf[8] = bfbits2f(z1.x & 0xffffu);  zf[9] = __uint_as_float(z1.x & 0xffff0000u);
    zf[10] = bfbits2f(z1.y & 0xffffu); zf[11] = __uint_as_float(z1.y & 0xffff0000u);
    zf[12] = bfbits2f(z1.z & 0xffffu); zf[13] = __uint_as_float(z1.z & 0xffff0000u);
    zf[14] = bfbits2f(z1.w & 0xffffu); zf[15] = __uint_as_float(z1.w & 0xffff0000u);

#pragma unroll
    for (int i = 0; i < 16; ++i) a[i] = fmaxf(a[i] * iv + zf[i], 0.0f);

    ushort_t* op = out + (size_t)w * 256 + l * 16;
    uint4 s0, s1;
    s0.x = pk2bf(a[0], a[1]);   s0.y = pk2bf(a[2], a[3]);
    s0.z = pk2bf(a[4], a[5]);   s0.w = pk2bf(a[6], a[7]);
    s1.x = pk2bf(a[8], a[9]);   s1.y = pk2bf(a[10], a[11]);
    s1.z = pk2bf(a[12], a[13]); s1.w = pk2bf(a[14], a[15]);
    *(uint4*)op = s0;
    *(uint4*)(op + 8) = s1;
}

// ---------------- merged MFMA GEMM, 2-phase double-buffered ----------------
// 128 rows x 256 out-cols per block; BK=32, NT=KTOT/32 tiles, dbuf LDS 2x24KB.
// Per tile: STAGE(next) issued BEFORE COMPUTE(cur); ONE barrier per tile (T3-minimum).
// MODE 0 (L1): out0 = relu(acc + bias[col]) over 256 bf16 cols.
// MODE 1 (dual): out0[lcol] = fp8(acc0); out1[lcol] = bf16(acc1 + bias[lcol]).
template <int KH, bool CONCAT, int MODE>
__global__ __launch_bounds__(256) void mfma_gemm256(const ushort_t* __restrict__ A,
                                                    const ushort_t* __restrict__ A2,
                                                    const ushort_t* __restrict__ WT,
                                                    const float* __restrict__ bias,
                                                    void* __restrict__ out0p, int ld0,
                                                    ushort_t* __restrict__ out1, int ld1) {
    constexpr int KTOT = CONCAT ? 2 * KH : KH;
    constexpr int BK = 32;
    constexpr int NT = KTOT / BK;
    __shared__ ushort_t smem[2][12288];   // per buf: A 4096 ush (8KB) + B 8192 ush (16KB)

    const int tid = threadIdx.x;
    const int lane = tid & 63;
    const int w = tid >> 6;
    const int wr = w >> 1, wc = w & 1;
    const int n0 = blockIdx.x * 128;

    const int srow = lane >> 2;                       // 0..15 row within chunk
    const int skc = (lane & 3) ^ ((srow >> 1) & 3);   // pre-swizzled 16B slot

    f32x4 acc0[4][4], acc1[4][4];
#pragma unroll
    for (int m = 0; m < 4; ++m)
#pragma unroll
        for (int n = 0; n < 4; ++n) {
            acc0[m][n] = (f32x4){0.f, 0.f, 0.f, 0.f};
            acc1[m][n] = (f32x4){0.f, 0.f, 0.f, 0.f};
        }

    auto STAGE = [&](int b, int t) {
        const int k0 = t * BK;
        const ushort_t* Asrc = A;
        int ak = k0;
        if (CONCAT && k0 >= KH) { Asrc = A2; ak = k0 - KH; }
#pragma unroll
        for (int i = 0; i < 2; ++i) {
            const int ci = w * 2 + i;
            int grow = n0 + ci * 16 + srow;
            grow = min(grow, N_NODES - 1);
            const ushort_t* g = Asrc + (size_t)grow * KH + ak + skc * 8;
            __builtin_amdgcn_global_load_lds((const unsigned int*)g,
                                             (unsigned int*)(&smem[b][ci * 512]), 16, 0, 0);
        }
#pragma unroll
        for (int i = 0; i < 4; ++i) {
            const int ci = w * 4 + i;
            const int jrow = ci * 16 + srow;
            const ushort_t* g = WT + (size_t)jrow * KTOT + k0 + skc * 8;
            __builtin_amdgcn_global_load_lds((const unsigned int*)g,
                                             (unsigned int*)(&smem[b][4096 + ci * 512]), 16, 0, 0);
        }
    };

    auto COMPUTE = [&](int b) {
        const int kc = lane >> 4;
        bf16x8 af[4], b0[4], b1[4];
#pragma unroll
        for (int m = 0; m < 4; ++m) {
            const int row = wr * 64 + m * 16 + (lane & 15);
            const int slot = kc ^ ((row >> 1) & 3);
            af[m] = *(const bf16x8*)((const char*)&smem[b][0] + row * 64 + slot * 16);
        }
#pragma unroll
        for (int n = 0; n < 4; ++n) {
            const int r0 = wc * 64 + n * 16 + (lane & 15);
            const int r1 = 128 + r0;
            const int s0 = kc ^ ((r0 >> 1) & 3);
            const int s1 = kc ^ ((r1 >> 1) & 3);
            b0[n] = *(const bf16x8*)((const char*)&smem[b][4096] + r0 * 64 + s0 * 16);
            b1[n] = *(const bf16x8*)((const char*)&smem[b][4096] + r1 * 64 + s1 * 16);
        }
#pragma unroll
        for (int m = 0; m < 4; ++m)
#pragma unroll
            for (int n = 0; n < 4; ++n) {
                acc0[m][n] = __builtin_amdgcn_mfma_f32_16x16x32_bf16(af[m], b0[n],
                                                                     acc0[m][n], 0, 0, 0);
                acc1[m][n] = __builtin_amdgcn_mfma_f32_16x16x32_bf16(af[m], b1[n],
                                                                     acc1[m][n], 0, 0, 0);
            }
    };

    STAGE(0, 0);
    __syncthreads();
    int cur = 0;
#pragma unroll
    for (int t = 0; t < NT - 1; ++t) {
        STAGE(cur ^ 1, t + 1);
        COMPUTE(cur);
        __syncthreads();
        cur ^= 1;
    }
    COMPUTE(cur);

    const int c15 = lane & 15;
    const int r4 = (lane >> 4) * 4;
#pragma unroll
    for (int m = 0; m < 4; ++m) {
#pragma unroll
        for (int q = 0; q < 4; ++q) {
            const int row_g = n0 + wr * 64 + m * 16 + r4 + q;
            if (row_g >= N_NODES) continue;
#pragma unroll
            for (int n = 0; n < 4; ++n) {
                const int lcol = wc * 64 + n * 16 + c15;
                const float v0 = acc0[m][n][q];
                const float v1 = acc1[m][n][q];
                if constexpr (MODE == 0) {
                    ushort_t* o = (ushort_t*)out0p;
                    o[(size_t)row_g * ld0 + lcol] = f2bfbits(fmaxf(v0 + bias[lcol], 0.0f));
                    o[(size_t)row_g * ld0 + 128 + lcol] =
                        f2bfbits(fmaxf(v1 + bias[128 + lcol], 0.0f));
                } else {
                    ((uchar_t*)out0p)[(size_t)row_g * ld0 + lcol] = f2fp8(v0);
                    out1[(size_t)row_g * ld1 + lcol] = f2bfbits(v1 + bias[lcol]);
                }
            }
        }
    }
}

// ---------------- launch ----------------
extern "C" void kernel_launch(void* const* d_in, const int* in_sizes, int n_in,
                              void* d_out, int out_size, void* d_ws, size_t ws_size,
                              hipStream_t stream) {
    const float* x   = (const float*)d_in[0];
    const int*   ei  = (const int*)d_in[1];
    const float* Wl1 = (const float*)d_in[2];
    const float* Wr1 = (const float*)d_in[3];
    const float* b1  = (const float*)d_in[4];
    const float* Wl2 = (const float*)d_in[5];
    const float* Wr2 = (const float*)d_in[6];
    const float* b2  = (const float*)d_in[7];
    const float* Wl3 = (const float*)d_in[8];
    const float* Wr3 = (const float*)d_in[9];
    const float* b3  = (const float*)d_in[10];

    const int E = in_sizes[1] / 2;
    const int* src = ei;
    const int* dst = ei + E;
    const int N = N_NODES;
    const int NC = (E + CHUNK - 1) / CHUNK;        // 391 @ 1.6M
    const int nH = NBUK * NC;                       // 152,881

    // ---- workspace arena (149.6 MB; 154.6 MB proven available) ----
    char* ws = (char*)d_ws;
    float* invd = (float*)(ws + 0);                  // 400,000
    int* cnt    = (int*)(ws + 400000);               // 400,000
    int* roff   = (int*)(ws + 800000);               // 400,016
    int* bsum   = (int*)(ws + 1200016);              // 1,024
    int* H      = (int*)(ws + 1201040);              // (nH+1)*4 = 611,528
    ushort_t* WT1  = (ushort_t*)(ws + 1812568);      // 131,072 (L1 k-concat, 256 rows)
    ushort_t* WT2A = (ushort_t*)(ws + 1943640);      // 131,072
    ushort_t* WT2B = (ushort_t*)(ws + 2074712);      // 131,072
    ushort_t* WT3  = (ushort_t*)(ws + 2205784);      // 131,072
    uint2* tmp  = (uint2*)(ws + 2336864);            // 12,800,000 (CSR build; then fp8 Y 128c)
    int* csr    = (int*)(ws + 15136864);             // 6,400,000
    ushort_t* h1 = (ushort_t*)(ws + 21536864);       // 51,200,000
    ushort_t* h2 = (ushort_t*)(ws + 72736864);       // 51,200,000
    ushort_t* M1 = h2;                                // alias (dead during L1)
    ushort_t* T1 = (ushort_t*)(ws + 123936864);      // 25,600,000 (bf16 x; then fp8 Y2 256c)
    const size_t WS_NEED = 149536864;
    if (ws_size < WS_NEED) return;

    uchar_t* T8  = (uchar_t*)tmp;      // 128-col fp8 rows (x in L1, Y3 in L3)
    uchar_t* T1a = (uchar_t*)T1;       // 256-col fp8 Y2 rows (L2; T1 dead after L1 GEMM)
    ushort_t* Zd = (ushort_t*)d_out;   // L2 Z scratch, N x 256 bf16 (d_out dead until L3)
    ushort_t* Zh = h1;                 // L3 Z scratch (h1 dead after L2)

    const int GX = (N + 127) / 128;
    const int NBH = (nH + 1023) / 1024;   // 150
    const int NBN = (N + 1023) / 1024;    // 98

    // ---- CSR build: atomic-free two-level bucket sort (10 launches) ----
    hist1<<<NC, 256, 0, stream>>>(dst, H, E, NC);
    scan1<<<NBH, 256, 0, stream>>>(H, H, bsum, nH);
    scan2<<<1, 256, 0, stream>>>(bsum, NBH);
    scan3<<<(nH + 256) / 256, 256, 0, stream>>>(H, bsum, nH, E);
    binA<<<NC, 256, 0, stream>>>(src, dst, H, tmp, E, NC);
    hist2_inv<<<NBUK, 256, 0, stream>>>(tmp, H, cnt, invd, NC);
    scan1<<<NBN, 256, 0, stream>>>(cnt, roff, bsum, N);
    scan2<<<1, 256, 0, stream>>>(bsum, NBN);
    scan3<<<(N + 256) / 256, 256, 0, stream>>>(roff, bsum, N, E);
    scatter2<<<NBUK, 256, 0, stream>>>(tmp, H, roff, csr, NC);

    // ---- weight prep (3 launches) ----
    cvt_transpose<<<(128 * 256 + 255) / 256, 256, 0, stream>>>(Wl1, WT1, 128, 256, 0, 256);
    cvt_transpose<<<(128 * 256 + 255) / 256, 256, 0, stream>>>(Wr1, WT1, 128, 256, 128, 256);
    cvt6<<<dim3(128, 6), 256, 0, stream>>>(Wl2, Wr2, Wl3, Wr3, WT2A, WT2B, WT3);

    // ---- layer 1: fp8 aggregate-first + merged concat GEMM ----
    round_both<<<(N * 128 / 4 + 255) / 256, 256, 0, stream>>>(x, T1, T8, (long)N * 128);
    gather_mean<false, ushort_t><<<(N * 64 + 255) / 256, 256, 0, stream>>>(
        T8, nullptr, roff, csr, invd, M1, 128, 0);
    mfma_gemm256<128, true, 0><<<GX, 256, 0, stream>>>(
        M1, T1, WT1, b1, h1, 256, nullptr, 0);

    // ---- layer 2: 2 dual GEMMs into full-width Y2/Z2, then ONE 256-col gather ----
    mfma_gemm256<256, false, 1><<<GX, 256, 0, stream>>>(
        h1, nullptr, WT2A, b2 + 0, T1a, 256, Zd, 256);
    mfma_gemm256<256, false, 1><<<GX, 256, 0, stream>>>(
        h1, nullptr, WT2B, b2 + 128, T1a + 128, 256, Zd + 128, 256);
    gather256<<<(N * 64 + 255) / 256, 256, 0, stream>>>(
        T1a, Zd, roff, csr, invd, h2);

    // ---- layer 3: dual GEMM (Y3 fp8 -> T8, Z -> Zh) + fused gather, f32 out ----
    mfma_gemm256<256, false, 1><<<GX, 256, 0, stream>>>(
        h2, nullptr, WT3, b3, T8, 128, Zh, 128);
    gather_mean<true, float><<<(N * 64 + 255) / 256, 256, 0, stream>>>(
        T8, Zh, roff, csr, invd, (float*)d_out, 128, 0);
}